// Round 18
// baseline (2744.969 us; speedup 1.0000x reference)
//
#include <hip/hip_runtime.h>
#include <math.h>

#define BB  256
#define TT  2048
#define VV  64
#define DD  50
#define HH  50
#define HIDN 100

// [tok][j] = seqFMA_d(embed[tok][d]*Wx[d][j]) + b_rnn[j]; cols 50..63 = 0.
__device__ float g_emWxb[VV * 64];
// [c][i] = W1[i][c], i 50..63 = 0 (contiguous 256B rows -> wide s_loads).
__device__ float g_W1T[HIDN * 64];

// ---------------------------------------------------------------------------
// XLA/Eigen fast-tanh, FMA-contracted Horner. BIT-EXACT with the reference
// trajectory (R6-R17 pass, absmax 0.015625). Do not touch.
// ---------------------------------------------------------------------------
__device__ __forceinline__ float xla_tanhf_fma(float x) {
#pragma clang fp contract(off)
  float ax = fabsf(x);
  float cx = fminf(fmaxf(x, -7.90531110763549805f), 7.90531110763549805f);
  float x2 = cx * cx;
  float p = -2.76076847742355e-16f;
  p = fmaf(x2, p, 2.00018790482477e-13f);
  p = fmaf(x2, p, -8.60467152213735e-11f);
  p = fmaf(x2, p, 5.12229709037114e-08f);
  p = fmaf(x2, p, 1.48572235717979e-05f);
  p = fmaf(x2, p, 6.37261928875436e-04f);
  p = fmaf(x2, p, 4.89352455891786e-03f);
  p = cx * p;
  float q = 1.19825839466702e-06f;
  q = fmaf(x2, q, 1.18534705686654e-04f);
  q = fmaf(x2, q, 2.26843463243900e-03f);
  q = fmaf(x2, q, 4.89352518554385e-03f);
  float r = p / q;
  return (ax < 0.0004f) ? x : r;
}

// ---------------------------------------------------------------------------
// K1: xp table, Eigen-gemm bit-emulation (unchanged from passing R6).
// ---------------------------------------------------------------------------
__global__ __launch_bounds__(256) void prep_kernel(
    const float* __restrict__ embed, const float* __restrict__ Wx,
    const float* __restrict__ b_rnn) {
#pragma clang fp contract(off)
  int o = blockIdx.x * 256 + threadIdx.x;
  if (o >= VV * 64) return;
  int v = o >> 6, j = o & 63;
  float val = 0.f;
  if (j < HH) {
    float s = 0.f;
    for (int d = 0; d < DD; ++d)
      s = fmaf(embed[v * DD + d], Wx[d * HH + j], s);
    val = s + b_rnn[j];
  }
  g_emWxb[o] = val;
}

// K1b: W1 transpose (pure data movement, bit-exact trivially).
__global__ __launch_bounds__(256) void prep2_kernel(const float* __restrict__ W1) {
  int o = blockIdx.x * 256 + threadIdx.x;
  if (o >= HIDN * 64) return;
  int c = o >> 6, i = o & 63;
  g_W1T[o] = (i < HH) ? W1[i * HIDN + c] : 0.f;
}

// ---------------------------------------------------------------------------
// K2: recurrence — EXACT R11 (541us), its structural floor:
// ~240 LDS write->read round-trip + 200 bit-exact dep-FMA chain + ~150 tanh
// (incl IEEE div) + ~45 misc = 634 cyc/step. All transport variants measured:
// barrier-LDS 680 (R6), readlane 737 (R9), bpermute 737 (R10), stagger null
// (R14), dual-row 1250 (R16), readlane+LDS split 700 (R17). FROZEN.
// Bit-critical: 50x fmaf ascending i, single acc; pre = xp + acc;
// xla_tanhf_fma. Chaos gain ~1.3e7 (absmax must stay exactly 0.015625).
// ---------------------------------------------------------------------------
__global__ __launch_bounds__(64) void rnn_kernel(
    const int* __restrict__ inputs, const float* __restrict__ Wh,
    float* hs) {
#pragma clang fp contract(off)
  const int b = blockIdx.x;
  const int lane = threadIdx.x;

  __shared__ __align__(16) float emw[VV * 64];  // 16 KB
  __shared__ int toks[TT];                      // 8 KB
  __shared__ __align__(16) float hshare[64];

  for (int o = lane; o < VV * 64; o += 64) emw[o] = g_emWxb[o];
  const int* rowp = inputs + (size_t)b * TT;
  for (int t = lane; t < TT; t += 64) toks[t] = rowp[t];

  float whcol[HH];
#pragma unroll
  for (int i = 0; i < HH; ++i)
    whcol[i] = (lane < HH) ? Wh[i * HH + lane] : 0.f;

  hshare[lane] = 0.f;   // h(-1) = 0
  __syncthreads();      // once (staging)

  float* outp = hs + (size_t)b * TT * 64;
  float h = 0.f;
  float xp = emw[toks[0] * 64 + lane];
  const float4* hp = reinterpret_cast<const float4*>(hshare);

#define FMA4(v, base)                         \
  acc = fmaf((v).x, whcol[(base) + 0], acc);  \
  acc = fmaf((v).y, whcol[(base) + 1], acc);  \
  acc = fmaf((v).z, whcol[(base) + 2], acc);  \
  acc = fmaf((v).w, whcol[(base) + 3], acc);

  for (int t = 0; t < TT; ++t) {
    float4 h0 = hp[0];
    float4 h1 = hp[1];
    float4 h2 = hp[2];
    float4 h3 = hp[3];
    float acc = 0.f;
    FMA4(h0, 0)  float4 h4 = hp[4];
    FMA4(h1, 4)  float4 h5 = hp[5];
    FMA4(h2, 8)  float4 h6 = hp[6];
    FMA4(h3, 12) float4 h7 = hp[7];
    FMA4(h4, 16) float4 h8 = hp[8];
    FMA4(h5, 20) float4 h9 = hp[9];
    FMA4(h6, 24) float4 h10 = hp[10];
    FMA4(h7, 28) float4 h11 = hp[11];
    FMA4(h8, 32) float4 h12 = hp[12];
    FMA4(h9, 36)
    FMA4(h10, 40)
    FMA4(h11, 44)
    acc = fmaf(h12.x, whcol[48], acc);
    acc = fmaf(h12.y, whcol[49], acc);
    float pre = xp + acc;

    int tn = toks[(t + 1 < TT) ? (t + 1) : (TT - 1)];
    float xpn = emw[tn * 64 + lane];

    h = xla_tanhf_fma(pre);
    hshare[lane] = h;                  // publish (same-wave RAW, no barrier)
    outp[(size_t)t * 64 + lane] = h;   // coalesced fire-and-forget
    xp = xpn;
  }
#undef FMA4
}

// ---------------------------------------------------------------------------
// K3: MLP head, 8-WAY c-unroll. Theory: R14's 4-way (175us, VALU ~43%) is
// limited by just-in-time s_load waits each c-group; 8 independent chains
// double the FMA work per wait cluster and let the compiler batch wider
// s_load_dwordx16 runs. Bit-exact: each a-chain ascending i (= R6 chain);
// each logit element receives updates in ascending c (a0..a7 = c..c+7);
// relu after +b1. (absmax must stay exactly 0.015625.)
// hs/out may alias -> NO restrict; thread r reads row r before writing it.
// ---------------------------------------------------------------------------
__global__ __launch_bounds__(256) void head_kernel(
    const float* hs, const float* __restrict__ b1,
    const float* __restrict__ W2, const float* __restrict__ b2,
    float* out) {
#pragma clang fp contract(off)
  const int r = blockIdx.x * 256 + threadIdx.x;  // 0 .. B*T-1
  const float* hrow = hs + (size_t)r * 64;

  float h[52];
#pragma unroll
  for (int q = 0; q < 13; ++q) {     // hrow is 256B-aligned
    float4 v = *reinterpret_cast<const float4*>(hrow + 4 * q);
    h[4 * q + 0] = v.x;
    h[4 * q + 1] = v.y;
    h[4 * q + 2] = v.z;
    h[4 * q + 3] = v.w;
  }

  float logit[VV];
#pragma unroll
  for (int jj = 0; jj < VV; ++jj) logit[jj] = b2[jj];

  for (int c = 0; c < HIDN; c += 8) {   // 12 full iterations + tail of 4
    float a[8];
#pragma unroll
    for (int u = 0; u < 8; ++u) a[u] = 0.f;
#pragma unroll
    for (int i = 0; i < HH; ++i) {      // 8 independent chains, per-chain order = R6
      float hv = h[i];
      const float* wrow = g_W1T + c * 64 + i;   // W1T[c+u][i] at wrow[u*64]
      a[0] = fmaf(hv, wrow[0 * 64], a[0]);
      a[1] = fmaf(hv, wrow[1 * 64], a[1]);
      a[2] = fmaf(hv, wrow[2 * 64], a[2]);
      a[3] = fmaf(hv, wrow[3 * 64], a[3]);
      if (c + 4 < HIDN) {
        a[4] = fmaf(hv, wrow[4 * 64], a[4]);
        a[5] = fmaf(hv, wrow[5 * 64], a[5]);
        a[6] = fmaf(hv, wrow[6 * 64], a[6]);
        a[7] = fmaf(hv, wrow[7 * 64], a[7]);
      }
    }
    const int nu = (c + 4 < HIDN) ? 8 : 4;   // HIDN=100 -> last group has 4
#pragma unroll
    for (int u = 0; u < 8; ++u) {
      if (u < nu) {
        a[u] += b1[c + u];
        a[u] = fmaxf(a[u], 0.f);
      }
    }
#pragma unroll
    for (int jj = 0; jj < VV; ++jj) {   // ascending-c update order = R6
      float acc = logit[jj];
      acc = fmaf(a[0], W2[(c + 0) * VV + jj], acc);
      acc = fmaf(a[1], W2[(c + 1) * VV + jj], acc);
      acc = fmaf(a[2], W2[(c + 2) * VV + jj], acc);
      acc = fmaf(a[3], W2[(c + 3) * VV + jj], acc);
      if (c + 4 < HIDN) {
        acc = fmaf(a[4], W2[(c + 4) * VV + jj], acc);
        acc = fmaf(a[5], W2[(c + 5) * VV + jj], acc);
        acc = fmaf(a[6], W2[(c + 6) * VV + jj], acc);
        acc = fmaf(a[7], W2[(c + 7) * VV + jj], acc);
      }
      logit[jj] = acc;
    }
  }

  float* orow = out + (size_t)r * 64;
#pragma unroll
  for (int q = 0; q < 16; ++q) {
    float4 v;
    v.x = logit[4 * q + 0];
    v.y = logit[4 * q + 1];
    v.z = logit[4 * q + 2];
    v.w = logit[4 * q + 3];
    *reinterpret_cast<float4*>(orow + 4 * q) = v;
  }
}

// ---------------------------------------------------------------------------
extern "C" void kernel_launch(void* const* d_in, const int* in_sizes, int n_in,
                              void* d_out, int out_size, void* d_ws, size_t ws_size,
                              hipStream_t stream) {
  // Map inputs by element-count signature (dict order breaks the Wx/Wh tie).
  const void* p[9] = {nullptr};
  const int want[9] = {BB * TT, VV * DD, DD * HH, HH * HH, HH,
                       HH * HIDN, HIDN, HIDN * VV, VV};
  bool used[32] = {false};
  for (int k = 0; k < 9; ++k)
    for (int i = 0; i < n_in && i < 32; ++i)
      if (!used[i] && in_sizes[i] == want[k]) { p[k] = d_in[i]; used[i] = true; break; }

  const int*   inputs = (const int*)  p[0];
  const float* embed  = (const float*)p[1];
  const float* Wx     = (const float*)p[2];
  const float* Wh     = (const float*)p[3];
  const float* b_rnn  = (const float*)p[4];
  const float* W1     = (const float*)p[5];
  const float* b1     = (const float*)p[6];
  const float* W2     = (const float*)p[7];
  const float* b2     = (const float*)p[8];

  float* out = (float*)d_out;
  float* hs = (ws_size >= (size_t)(BB * TT * 64) * sizeof(float))
                  ? (float*)d_ws : out;

  prep_kernel<<<(VV * 64 + 255) / 256, 256, 0, stream>>>(embed, Wx, b_rnn);
  prep2_kernel<<<(HIDN * 64 + 255) / 256, 256, 0, stream>>>(W1);
  rnn_kernel<<<BB, 64, 0, stream>>>(inputs, Wh, hs);
  head_kernel<<<(BB * TT) / 256, 256, 0, stream>>>(hs, b1, W2, b2, out);
}

// Round 19
// 1219.700 us; speedup vs baseline: 2.2505x; 2.2505x over previous
//
#include <hip/hip_runtime.h>
#include <math.h>

#define BB  256
#define TT  2048
#define VV  64
#define DD  50
#define HH  50
#define HIDN 100

// [tok][j] = seqFMA_d(embed[tok][d]*Wx[d][j]) + b_rnn[j]; cols 50..63 = 0.
__device__ float g_emWxb[VV * 64];
// [c][i] = W1[i][c], i 50..63 = 0 (contiguous 256B rows).
__device__ float g_W1T[HIDN * 64];

// ---------------------------------------------------------------------------
// XLA/Eigen fast-tanh, FMA-contracted Horner. BIT-EXACT with the reference
// trajectory (R6-R18 pass, absmax 0.015625). Do not touch.
// ---------------------------------------------------------------------------
__device__ __forceinline__ float xla_tanhf_fma(float x) {
#pragma clang fp contract(off)
  float ax = fabsf(x);
  float cx = fminf(fmaxf(x, -7.90531110763549805f), 7.90531110763549805f);
  float x2 = cx * cx;
  float p = -2.76076847742355e-16f;
  p = fmaf(x2, p, 2.00018790482477e-13f);
  p = fmaf(x2, p, -8.60467152213735e-11f);
  p = fmaf(x2, p, 5.12229709037114e-08f);
  p = fmaf(x2, p, 1.48572235717979e-05f);
  p = fmaf(x2, p, 6.37261928875436e-04f);
  p = fmaf(x2, p, 4.89352455891786e-03f);
  p = cx * p;
  float q = 1.19825839466702e-06f;
  q = fmaf(x2, q, 1.18534705686654e-04f);
  q = fmaf(x2, q, 2.26843463243900e-03f);
  q = fmaf(x2, q, 4.89352518554385e-03f);
  float r = p / q;
  return (ax < 0.0004f) ? x : r;
}

// ---------------------------------------------------------------------------
// K1: xp table, Eigen-gemm bit-emulation (unchanged from passing R6).
// ---------------------------------------------------------------------------
__global__ __launch_bounds__(256) void prep_kernel(
    const float* __restrict__ embed, const float* __restrict__ Wx,
    const float* __restrict__ b_rnn) {
#pragma clang fp contract(off)
  int o = blockIdx.x * 256 + threadIdx.x;
  if (o >= VV * 64) return;
  int v = o >> 6, j = o & 63;
  float val = 0.f;
  if (j < HH) {
    float s = 0.f;
    for (int d = 0; d < DD; ++d)
      s = fmaf(embed[v * DD + d], Wx[d * HH + j], s);
    val = s + b_rnn[j];
  }
  g_emWxb[o] = val;
}

// K1b: W1 transpose (pure data movement, bit-exact trivially).
__global__ __launch_bounds__(256) void prep2_kernel(const float* __restrict__ W1) {
  int o = blockIdx.x * 256 + threadIdx.x;
  if (o >= HIDN * 64) return;
  int c = o >> 6, i = o & 63;
  g_W1T[o] = (i < HH) ? W1[i * HIDN + c] : 0.f;
}

// ---------------------------------------------------------------------------
// K2: recurrence — EXACT R11 (541us), its structural floor:
// ~240 LDS write->read round-trip + 200 bit-exact dep-FMA chain + ~150 tanh
// (incl IEEE div) + ~45 misc = 634 cyc/step. Transport variants measured:
// barrier-LDS 680 (R6), readlane 737 (R9), bpermute 737 (R10), stagger null
// (R14), dual-row 1250 (R16), readlane+LDS split 700 (R17). FROZEN.
// Bit-critical: 50x fmaf ascending i, single acc; pre = xp + acc;
// xla_tanhf_fma. Chaos gain ~1.3e7 (absmax must stay exactly 0.015625).
// ---------------------------------------------------------------------------
__global__ __launch_bounds__(64) void rnn_kernel(
    const int* __restrict__ inputs, const float* __restrict__ Wh,
    float* hs) {
#pragma clang fp contract(off)
  const int b = blockIdx.x;
  const int lane = threadIdx.x;

  __shared__ __align__(16) float emw[VV * 64];  // 16 KB
  __shared__ int toks[TT];                      // 8 KB
  __shared__ __align__(16) float hshare[64];

  for (int o = lane; o < VV * 64; o += 64) emw[o] = g_emWxb[o];
  const int* rowp = inputs + (size_t)b * TT;
  for (int t = lane; t < TT; t += 64) toks[t] = rowp[t];

  float whcol[HH];
#pragma unroll
  for (int i = 0; i < HH; ++i)
    whcol[i] = (lane < HH) ? Wh[i * HH + lane] : 0.f;

  hshare[lane] = 0.f;   // h(-1) = 0
  __syncthreads();      // once (staging)

  float* outp = hs + (size_t)b * TT * 64;
  float h = 0.f;
  float xp = emw[toks[0] * 64 + lane];
  const float4* hp = reinterpret_cast<const float4*>(hshare);

#define FMA4(v, base)                         \
  acc = fmaf((v).x, whcol[(base) + 0], acc);  \
  acc = fmaf((v).y, whcol[(base) + 1], acc);  \
  acc = fmaf((v).z, whcol[(base) + 2], acc);  \
  acc = fmaf((v).w, whcol[(base) + 3], acc);

  for (int t = 0; t < TT; ++t) {
    float4 h0 = hp[0];
    float4 h1 = hp[1];
    float4 h2 = hp[2];
    float4 h3 = hp[3];
    float acc = 0.f;
    FMA4(h0, 0)  float4 h4 = hp[4];
    FMA4(h1, 4)  float4 h5 = hp[5];
    FMA4(h2, 8)  float4 h6 = hp[6];
    FMA4(h3, 12) float4 h7 = hp[7];
    FMA4(h4, 16) float4 h8 = hp[8];
    FMA4(h5, 20) float4 h9 = hp[9];
    FMA4(h6, 24) float4 h10 = hp[10];
    FMA4(h7, 28) float4 h11 = hp[11];
    FMA4(h8, 32) float4 h12 = hp[12];
    FMA4(h9, 36)
    FMA4(h10, 40)
    FMA4(h11, 44)
    acc = fmaf(h12.x, whcol[48], acc);
    acc = fmaf(h12.y, whcol[49], acc);
    float pre = xp + acc;

    int tn = toks[(t + 1 < TT) ? (t + 1) : (TT - 1)];
    float xpn = emw[tn * 64 + lane];

    h = xla_tanhf_fma(pre);
    hshare[lane] = h;                  // publish (same-wave RAW, no barrier)
    outp[(size_t)t * 64 + lane] = h;   // coalesced fire-and-forget
    xp = xpn;
  }
#undef FMA4
}

// ---------------------------------------------------------------------------
// K3: MLP head = R14's 4-way c-unroll + VMEM-FORCED weight loads.
// R18 post-mortem: 8-way unroll w/ runtime branches spilled (VGPR=256,
// 370MB scratch traffic) -> reverted to 4-way. R14's 175us (vs 77 ideal) is
// s_load-bound: 11.4k uniform weight dwords/thread through ~100 SGPRs ->
// serialized lgkmcnt clusters. Fix: opaque-zero VGPR offset (inline asm)
// makes weight addresses opaque-uniform -> compiler emits global_load_
// dwordx4 (VMEM): 64-deep vmcnt queue, deep pipelining, no SGPR ceiling;
// all lanes hit the same L1 line (broadcast return). Addresses and VALUES
// identical; per-element fmaf chains identical (absmax must stay exactly
// 0.015625). hs/out may alias -> NO restrict.
// ---------------------------------------------------------------------------
__global__ __launch_bounds__(256) void head_kernel(
    const float* hs, const float* __restrict__ b1,
    const float* __restrict__ W2, const float* __restrict__ b2,
    float* out) {
#pragma clang fp contract(off)
  const int r = blockIdx.x * 256 + threadIdx.x;  // 0 .. B*T-1
  const float* hrow = hs + (size_t)r * 64;

  int zv = 0;
  asm volatile("" : "+v"(zv));   // opaque 0 in a VGPR -> forces VMEM weight path
  const float* W1v = g_W1T + zv;
  const float* W2v = W2 + zv;

  float h[52];
#pragma unroll
  for (int q = 0; q < 13; ++q) {     // hrow is 256B-aligned
    float4 v = *reinterpret_cast<const float4*>(hrow + 4 * q);
    h[4 * q + 0] = v.x;
    h[4 * q + 1] = v.y;
    h[4 * q + 2] = v.z;
    h[4 * q + 3] = v.w;
  }

  float logit[VV];
#pragma unroll
  for (int jj = 0; jj < VV; ++jj) logit[jj] = b2[jj];   // small, scalar path ok

  for (int c = 0; c < HIDN; c += 4) {   // 25 iterations
    const float4* w0 = reinterpret_cast<const float4*>(W1v + (c + 0) * 64);
    const float4* w1 = reinterpret_cast<const float4*>(W1v + (c + 1) * 64);
    const float4* w2c = reinterpret_cast<const float4*>(W1v + (c + 2) * 64);
    const float4* w3 = reinterpret_cast<const float4*>(W1v + (c + 3) * 64);
    float a0 = 0.f, a1 = 0.f, a2 = 0.f, a3 = 0.f;
#pragma unroll
    for (int q = 0; q < 12; ++q) {      // i = 4q..4q+3; per-chain ascending i = R6 order
      float4 u0 = w0[q], u1 = w1[q], u2 = w2c[q], u3 = w3[q];
      a0 = fmaf(h[4 * q + 0], u0.x, a0);
      a0 = fmaf(h[4 * q + 1], u0.y, a0);
      a0 = fmaf(h[4 * q + 2], u0.z, a0);
      a0 = fmaf(h[4 * q + 3], u0.w, a0);
      a1 = fmaf(h[4 * q + 0], u1.x, a1);
      a1 = fmaf(h[4 * q + 1], u1.y, a1);
      a1 = fmaf(h[4 * q + 2], u1.z, a1);
      a1 = fmaf(h[4 * q + 3], u1.w, a1);
      a2 = fmaf(h[4 * q + 0], u2.x, a2);
      a2 = fmaf(h[4 * q + 1], u2.y, a2);
      a2 = fmaf(h[4 * q + 2], u2.z, a2);
      a2 = fmaf(h[4 * q + 3], u2.w, a2);
      a3 = fmaf(h[4 * q + 0], u3.x, a3);
      a3 = fmaf(h[4 * q + 1], u3.y, a3);
      a3 = fmaf(h[4 * q + 2], u3.z, a3);
      a3 = fmaf(h[4 * q + 3], u3.w, a3);
    }
    {                                   // i = 48, 49 (tail of the 50-chain)
      float4 u0 = w0[12], u1 = w1[12], u2 = w2c[12], u3 = w3[12];
      a0 = fmaf(h[48], u0.x, a0); a0 = fmaf(h[49], u0.y, a0);
      a1 = fmaf(h[48], u1.x, a1); a1 = fmaf(h[49], u1.y, a1);
      a2 = fmaf(h[48], u2.x, a2); a2 = fmaf(h[49], u2.y, a2);
      a3 = fmaf(h[48], u3.x, a3); a3 = fmaf(h[49], u3.y, a3);
    }
    a0 += b1[c + 0]; a0 = fmaxf(a0, 0.f);
    a1 += b1[c + 1]; a1 = fmaxf(a1, 0.f);
    a2 += b1[c + 2]; a2 = fmaxf(a2, 0.f);
    a3 += b1[c + 3]; a3 = fmaxf(a3, 0.f);
    const float4* v0 = reinterpret_cast<const float4*>(W2v + (c + 0) * VV);
    const float4* v1 = reinterpret_cast<const float4*>(W2v + (c + 1) * VV);
    const float4* v2 = reinterpret_cast<const float4*>(W2v + (c + 2) * VV);
    const float4* v3 = reinterpret_cast<const float4*>(W2v + (c + 3) * VV);
#pragma unroll
    for (int q = 0; q < 16; ++q) {      // jj = 4q..4q+3
      float4 x0 = v0[q], x1 = v1[q], x2 = v2[q], x3 = v3[q];
      float acc;
      acc = logit[4 * q + 0];           // per-element order a0,a1,a2,a3 = R6
      acc = fmaf(a0, x0.x, acc);
      acc = fmaf(a1, x1.x, acc);
      acc = fmaf(a2, x2.x, acc);
      acc = fmaf(a3, x3.x, acc);
      logit[4 * q + 0] = acc;
      acc = logit[4 * q + 1];
      acc = fmaf(a0, x0.y, acc);
      acc = fmaf(a1, x1.y, acc);
      acc = fmaf(a2, x2.y, acc);
      acc = fmaf(a3, x3.y, acc);
      logit[4 * q + 1] = acc;
      acc = logit[4 * q + 2];
      acc = fmaf(a0, x0.z, acc);
      acc = fmaf(a1, x1.z, acc);
      acc = fmaf(a2, x2.z, acc);
      acc = fmaf(a3, x3.z, acc);
      logit[4 * q + 2] = acc;
      acc = logit[4 * q + 3];
      acc = fmaf(a0, x0.w, acc);
      acc = fmaf(a1, x1.w, acc);
      acc = fmaf(a2, x2.w, acc);
      acc = fmaf(a3, x3.w, acc);
      logit[4 * q + 3] = acc;
    }
  }

  float* orow = out + (size_t)r * 64;
#pragma unroll
  for (int q = 0; q < 16; ++q) {
    float4 v;
    v.x = logit[4 * q + 0];
    v.y = logit[4 * q + 1];
    v.z = logit[4 * q + 2];
    v.w = logit[4 * q + 3];
    *reinterpret_cast<float4*>(orow + 4 * q) = v;
  }
}

// ---------------------------------------------------------------------------
extern "C" void kernel_launch(void* const* d_in, const int* in_sizes, int n_in,
                              void* d_out, int out_size, void* d_ws, size_t ws_size,
                              hipStream_t stream) {
  // Map inputs by element-count signature (dict order breaks the Wx/Wh tie).
  const void* p[9] = {nullptr};
  const int want[9] = {BB * TT, VV * DD, DD * HH, HH * HH, HH,
                       HH * HIDN, HIDN, HIDN * VV, VV};
  bool used[32] = {false};
  for (int k = 0; k < 9; ++k)
    for (int i = 0; i < n_in && i < 32; ++i)
      if (!used[i] && in_sizes[i] == want[k]) { p[k] = d_in[i]; used[i] = true; break; }

  const int*   inputs = (const int*)  p[0];
  const float* embed  = (const float*)p[1];
  const float* Wx     = (const float*)p[2];
  const float* Wh     = (const float*)p[3];
  const float* b_rnn  = (const float*)p[4];
  const float* W1     = (const float*)p[5];
  const float* b1     = (const float*)p[6];
  const float* W2     = (const float*)p[7];
  const float* b2     = (const float*)p[8];

  float* out = (float*)d_out;
  float* hs = (ws_size >= (size_t)(BB * TT * 64) * sizeof(float))
                  ? (float*)d_ws : out;

  prep_kernel<<<(VV * 64 + 255) / 256, 256, 0, stream>>>(embed, Wx, b_rnn);
  prep2_kernel<<<(HIDN * 64 + 255) / 256, 256, 0, stream>>>(W1);
  rnn_kernel<<<BB, 64, 0, stream>>>(inputs, Wh, hs);
  head_kernel<<<(BB * TT) / 256, 256, 0, stream>>>(hs, b1, W2, b2, out);
}

// Round 20
// 728.269 us; speedup vs baseline: 3.7692x; 1.6748x over previous
//
#include <hip/hip_runtime.h>
#include <math.h>

#define BB  256
#define TT  2048
#define VV  64
#define DD  50
#define HH  50
#define HIDN 100

// [tok][j] = seqFMA_d(embed[tok][d]*Wx[d][j]) + b_rnn[j]; cols 50..63 = 0.
__device__ float g_emWxb[VV * 64];
// [c][i] = W1[i][c], i 50..63 = 0 (contiguous 256B rows -> wide s_loads).
__device__ float g_W1T[HIDN * 64];

// ---------------------------------------------------------------------------
// XLA/Eigen fast-tanh, FMA-contracted Horner. BIT-EXACT with the reference
// trajectory (R6-R19 pass, absmax 0.015625). Do not touch: clamp
// +-7.90531110763549805, fmaf Horner, IEEE f32 divide, |x|<4e-4 passthrough.
// ---------------------------------------------------------------------------
__device__ __forceinline__ float xla_tanhf_fma(float x) {
#pragma clang fp contract(off)
  float ax = fabsf(x);
  float cx = fminf(fmaxf(x, -7.90531110763549805f), 7.90531110763549805f);
  float x2 = cx * cx;
  float p = -2.76076847742355e-16f;
  p = fmaf(x2, p, 2.00018790482477e-13f);
  p = fmaf(x2, p, -8.60467152213735e-11f);
  p = fmaf(x2, p, 5.12229709037114e-08f);
  p = fmaf(x2, p, 1.48572235717979e-05f);
  p = fmaf(x2, p, 6.37261928875436e-04f);
  p = fmaf(x2, p, 4.89352455891786e-03f);
  p = cx * p;
  float q = 1.19825839466702e-06f;
  q = fmaf(x2, q, 1.18534705686654e-04f);
  q = fmaf(x2, q, 2.26843463243900e-03f);
  q = fmaf(x2, q, 4.89352518554385e-03f);
  float r = p / q;
  return (ax < 0.0004f) ? x : r;
}

// ---------------------------------------------------------------------------
// K1: xp table, Eigen-gemm bit-emulation (unchanged from passing R6).
// ---------------------------------------------------------------------------
__global__ __launch_bounds__(256) void prep_kernel(
    const float* __restrict__ embed, const float* __restrict__ Wx,
    const float* __restrict__ b_rnn) {
#pragma clang fp contract(off)
  int o = blockIdx.x * 256 + threadIdx.x;
  if (o >= VV * 64) return;
  int v = o >> 6, j = o & 63;
  float val = 0.f;
  if (j < HH) {
    float s = 0.f;
    for (int d = 0; d < DD; ++d)
      s = fmaf(embed[v * DD + d], Wx[d * HH + j], s);
    val = s + b_rnn[j];
  }
  g_emWxb[o] = val;
}

// K1b: W1 transpose (pure data movement, bit-exact trivially).
__global__ __launch_bounds__(256) void prep2_kernel(const float* __restrict__ W1) {
  int o = blockIdx.x * 256 + threadIdx.x;
  if (o >= HIDN * 64) return;
  int c = o >> 6, i = o & 63;
  g_W1T[o] = (i < HH) ? W1[i * HIDN + c] : 0.f;
}

// ---------------------------------------------------------------------------
// K2: recurrence — EXACT R11 (541us), its structural floor:
// ~240 LDS write->read round-trip + 200 bit-exact dep-FMA chain + ~150 tanh
// (incl IEEE div) + ~45 misc = 634 cyc/step. Transport variants measured:
// barrier-LDS 680 (R6), readlane 737 (R9), bpermute 737 (R10), stagger null
// (R14), dual-row 1250 (R16), readlane+LDS split 700 (R17). FROZEN.
// Bit-critical: 50x fmaf ascending i, single acc; pre = xp + acc;
// xla_tanhf_fma. Chaos gain ~1.3e7 (absmax must stay exactly 0.015625).
// ---------------------------------------------------------------------------
__global__ __launch_bounds__(64) void rnn_kernel(
    const int* __restrict__ inputs, const float* __restrict__ Wh,
    float* hs) {
#pragma clang fp contract(off)
  const int b = blockIdx.x;
  const int lane = threadIdx.x;

  __shared__ __align__(16) float emw[VV * 64];  // 16 KB
  __shared__ int toks[TT];                      // 8 KB
  __shared__ __align__(16) float hshare[64];

  for (int o = lane; o < VV * 64; o += 64) emw[o] = g_emWxb[o];
  const int* rowp = inputs + (size_t)b * TT;
  for (int t = lane; t < TT; t += 64) toks[t] = rowp[t];

  float whcol[HH];
#pragma unroll
  for (int i = 0; i < HH; ++i)
    whcol[i] = (lane < HH) ? Wh[i * HH + lane] : 0.f;

  hshare[lane] = 0.f;   // h(-1) = 0
  __syncthreads();      // once (staging)

  float* outp = hs + (size_t)b * TT * 64;
  float h = 0.f;
  float xp = emw[toks[0] * 64 + lane];
  const float4* hp = reinterpret_cast<const float4*>(hshare);

#define FMA4(v, base)                         \
  acc = fmaf((v).x, whcol[(base) + 0], acc);  \
  acc = fmaf((v).y, whcol[(base) + 1], acc);  \
  acc = fmaf((v).z, whcol[(base) + 2], acc);  \
  acc = fmaf((v).w, whcol[(base) + 3], acc);

  for (int t = 0; t < TT; ++t) {
    float4 h0 = hp[0];
    float4 h1 = hp[1];
    float4 h2 = hp[2];
    float4 h3 = hp[3];
    float acc = 0.f;
    FMA4(h0, 0)  float4 h4 = hp[4];
    FMA4(h1, 4)  float4 h5 = hp[5];
    FMA4(h2, 8)  float4 h6 = hp[6];
    FMA4(h3, 12) float4 h7 = hp[7];
    FMA4(h4, 16) float4 h8 = hp[8];
    FMA4(h5, 20) float4 h9 = hp[9];
    FMA4(h6, 24) float4 h10 = hp[10];
    FMA4(h7, 28) float4 h11 = hp[11];
    FMA4(h8, 32) float4 h12 = hp[12];
    FMA4(h9, 36)
    FMA4(h10, 40)
    FMA4(h11, 44)
    acc = fmaf(h12.x, whcol[48], acc);
    acc = fmaf(h12.y, whcol[49], acc);
    float pre = xp + acc;

    int tn = toks[(t + 1 < TT) ? (t + 1) : (TT - 1)];
    float xpn = emw[tn * 64 + lane];

    h = xla_tanhf_fma(pre);
    hshare[lane] = h;                  // publish (same-wave RAW, no barrier)
    outp[(size_t)t * 64 + lane] = h;   // coalesced fire-and-forget
    xp = xpn;
  }
#undef FMA4
}

// ---------------------------------------------------------------------------
// K3: MLP head — EXACT R14 (175us, the measured optimum). One THREAD per
// (b,t) row, 4-way c-unroll, W1T scalar loads. Experiment ledger: packed-f32
// 310 (R15), 8-way-unroll 2330 spill (R18), VMEM-forced 724 (R19) — all
// regressed; s_load path at 43% of VALU ideal is this structure's floor.
// Per-element chains bit-identical to R6 (absmax must stay exactly
// 0.015625). hs/out may alias -> NO restrict.
// ---------------------------------------------------------------------------
__global__ __launch_bounds__(256) void head_kernel(
    const float* hs, const float* __restrict__ b1,
    const float* __restrict__ W2, const float* __restrict__ b2,
    float* out) {
#pragma clang fp contract(off)
  const int r = blockIdx.x * 256 + threadIdx.x;  // 0 .. B*T-1
  const float* hrow = hs + (size_t)r * 64;

  float h[52];
#pragma unroll
  for (int q = 0; q < 13; ++q) {     // hrow is 256B-aligned
    float4 v = *reinterpret_cast<const float4*>(hrow + 4 * q);
    h[4 * q + 0] = v.x;
    h[4 * q + 1] = v.y;
    h[4 * q + 2] = v.z;
    h[4 * q + 3] = v.w;
  }

  float logit[VV];
#pragma unroll
  for (int jj = 0; jj < VV; ++jj) logit[jj] = b2[jj];

  for (int c = 0; c < HIDN; c += 4) {   // 25 iterations
    const float* w0 = g_W1T + (c + 0) * 64;
    const float* w1 = g_W1T + (c + 1) * 64;
    const float* w2c = g_W1T + (c + 2) * 64;
    const float* w3 = g_W1T + (c + 3) * 64;
    float a0 = 0.f, a1 = 0.f, a2 = 0.f, a3 = 0.f;
#pragma unroll
    for (int i = 0; i < HH; ++i) {      // 4 independent chains, per-chain order = R6
      a0 = fmaf(h[i], w0[i], a0);
      a1 = fmaf(h[i], w1[i], a1);
      a2 = fmaf(h[i], w2c[i], a2);
      a3 = fmaf(h[i], w3[i], a3);
    }
    a0 += b1[c + 0]; a0 = fmaxf(a0, 0.f);
    a1 += b1[c + 1]; a1 = fmaxf(a1, 0.f);
    a2 += b1[c + 2]; a2 = fmaxf(a2, 0.f);
    a3 += b1[c + 3]; a3 = fmaxf(a3, 0.f);
    const float* v0 = W2 + (c + 0) * VV;
    const float* v1 = W2 + (c + 1) * VV;
    const float* v2 = W2 + (c + 2) * VV;
    const float* v3 = W2 + (c + 3) * VV;
#pragma unroll
    for (int jj = 0; jj < VV; ++jj) {   // ascending-c update order = R6
      float acc = logit[jj];
      acc = fmaf(a0, v0[jj], acc);
      acc = fmaf(a1, v1[jj], acc);
      acc = fmaf(a2, v2[jj], acc);
      acc = fmaf(a3, v3[jj], acc);
      logit[jj] = acc;
    }
  }

  float* orow = out + (size_t)r * 64;
#pragma unroll
  for (int q = 0; q < 16; ++q) {
    float4 v;
    v.x = logit[4 * q + 0];
    v.y = logit[4 * q + 1];
    v.z = logit[4 * q + 2];
    v.w = logit[4 * q + 3];
    *reinterpret_cast<float4*>(orow + 4 * q) = v;
  }
}

// ---------------------------------------------------------------------------
extern "C" void kernel_launch(void* const* d_in, const int* in_sizes, int n_in,
                              void* d_out, int out_size, void* d_ws, size_t ws_size,
                              hipStream_t stream) {
  // Map inputs by element-count signature (dict order breaks the Wx/Wh tie).
  const void* p[9] = {nullptr};
  const int want[9] = {BB * TT, VV * DD, DD * HH, HH * HH, HH,
                       HH * HIDN, HIDN, HIDN * VV, VV};
  bool used[32] = {false};
  for (int k = 0; k < 9; ++k)
    for (int i = 0; i < n_in && i < 32; ++i)
      if (!used[i] && in_sizes[i] == want[k]) { p[k] = d_in[i]; used[i] = true; break; }

  const int*   inputs = (const int*)  p[0];
  const float* embed  = (const float*)p[1];
  const float* Wx     = (const float*)p[2];
  const float* Wh     = (const float*)p[3];
  const float* b_rnn  = (const float*)p[4];
  const float* W1     = (const float*)p[5];
  const float* b1     = (const float*)p[6];
  const float* W2     = (const float*)p[7];
  const float* b2     = (const float*)p[8];

  float* out = (float*)d_out;
  float* hs = (ws_size >= (size_t)(BB * TT * 64) * sizeof(float))
                  ? (float*)d_ws : out;

  prep_kernel<<<(VV * 64 + 255) / 256, 256, 0, stream>>>(embed, Wx, b_rnn);
  prep2_kernel<<<(HIDN * 64 + 255) / 256, 256, 0, stream>>>(W1);
  rnn_kernel<<<BB, 64, 0, stream>>>(inputs, Wh, hs);
  head_kernel<<<(BB * TT) / 256, 256, 0, stream>>>(hs, b1, W2, b2, out);
}